// Round 8
// baseline (296.308 us; speedup 1.0000x reference)
//
#include <hip/hip_runtime.h>
#include <hip/hip_bf16.h>
#include <stdint.h>

#define NCLS 36
#define HDIM 256
#define BSZ  32
#define LLOC 196
#define DIN  1024
#define NCH  9216          // NCLS*HDIM
#define XG_N 294912        // BSZ*NCH
#define SC_N 225792        // BSZ*NCLS*LLOC
#define V_N  1179648       // BSZ*NCLS*DIN

// ---------------------------------------------------------------------------
// kA: xg_part[ks][b][n] = sum_{k chunk128} gap[b][k]*Wg[k][n]
// grid (36 nt256, 8 ks, 2 bh16) = 576. 2 n per thread: each ds_read feeds 8 FMA.
__global__ __launch_bounds__(256) void kA_xg_part(
    const float* __restrict__ Wg, const float* __restrict__ gap,
    float* __restrict__ A) {
  __shared__ __align__(16) float4 gs[512];          // [16][32] = 8 KB
  const int tid = threadIdx.x;
  const int nt = blockIdx.x, ks = blockIdx.y, bh = blockIdx.z;
  const int kc = ks * 128, b0 = bh * 16;
  for (int i = tid; i < 512; i += 256) {
    int bi = i >> 5, pos = i & 31;
    gs[bi * 32 + pos] = *(const float4*)&gap[(size_t)(b0 + bi) * DIN + kc + pos * 4];
  }
  __syncthreads();
  const int g = tid >> 7, lane = tid & 127;
  const int n = nt * 256 + lane;
  float acc0[8] = {0,0,0,0,0,0,0,0};
  float acc1[8] = {0,0,0,0,0,0,0,0};
  const float* wp = Wg + (size_t)kc * NCH + n;
  for (int k4 = 0; k4 < 32; ++k4) {
    float w10 = wp[(size_t)(k4 * 4 + 0) * NCH];
    float w11 = wp[(size_t)(k4 * 4 + 1) * NCH];
    float w12 = wp[(size_t)(k4 * 4 + 2) * NCH];
    float w13 = wp[(size_t)(k4 * 4 + 3) * NCH];
    float w20 = wp[(size_t)(k4 * 4 + 0) * NCH + 128];
    float w21 = wp[(size_t)(k4 * 4 + 1) * NCH + 128];
    float w22 = wp[(size_t)(k4 * 4 + 2) * NCH + 128];
    float w23 = wp[(size_t)(k4 * 4 + 3) * NCH + 128];
    #pragma unroll
    for (int bi = 0; bi < 8; ++bi) {
      float4 gv = gs[(g * 8 + bi) * 32 + k4];        // LDS broadcast
      acc0[bi] += gv.x * w10 + gv.y * w11 + gv.z * w12 + gv.w * w13;
      acc1[bi] += gv.x * w20 + gv.y * w21 + gv.z * w22 + gv.w * w23;
    }
  }
  #pragma unroll
  for (int bi = 0; bi < 8; ++bi) {
    size_t o = (size_t)ks * XG_N + (size_t)(b0 + g * 8 + bi) * NCH + n;
    A[o]       = acc0[bi];
    A[o + 128] = acc1[bi];
  }
}

// ---------------------------------------------------------------------------
// kC: V[b][c][k] = sum_h xg[b][c,h]*Wl[k][c,h], xg = bg + sum8 partials
// (folded into stage). grid (36 c, 4 kq256, 4 bq8) = 576. 2 k per thread.
__global__ __launch_bounds__(256) void kC_V(
    const float* __restrict__ Wl, const float* __restrict__ A,
    const float* __restrict__ bg, float* __restrict__ V) {
  __shared__ __align__(16) float4 xs[512];          // [8][64] = 8 KB
  const int tid = threadIdx.x;
  const int c = blockIdx.x, kq = blockIdx.y, b0 = blockIdx.z * 8;
  for (int i = tid; i < 512; i += 256) {
    int bi = i >> 6, j = i & 63;
    size_t off = (size_t)(b0 + bi) * NCH + c * HDIM + j * 4;
    float4 s = *(const float4*)&bg[c * HDIM + j * 4];
    #pragma unroll
    for (int p = 0; p < 8; ++p) {
      float4 t = *(const float4*)&A[(size_t)p * XG_N + off];
      s.x += t.x; s.y += t.y; s.z += t.z; s.w += t.w;
    }
    xs[bi * 64 + j] = s;
  }
  __syncthreads();
  const int g = tid >> 7, lane = tid & 127;
  const int k1 = kq * 256 + lane, k2 = k1 + 128;
  float acc0[4] = {0,0,0,0};
  float acc1[4] = {0,0,0,0};
  const float* wl1 = Wl + (size_t)k1 * NCH + c * HDIM;
  const float* wl2 = Wl + (size_t)k2 * NCH + c * HDIM;
  for (int j = 0; j < 64; ++j) {
    float4 w1 = *(const float4*)&wl1[j * 4];
    float4 w2 = *(const float4*)&wl2[j * 4];
    #pragma unroll
    for (int bi = 0; bi < 4; ++bi) {
      float4 x = xs[(g * 4 + bi) * 64 + j];          // LDS broadcast
      acc0[bi] += w1.x * x.x + w1.y * x.y + w1.z * x.z + w1.w * x.w;
      acc1[bi] += w2.x * x.x + w2.y * x.y + w2.z * x.z + w2.w * x.w;
    }
  }
  #pragma unroll
  for (int bi = 0; bi < 4; ++bi) {
    size_t o = (size_t)((b0 + g * 4 + bi) * NCLS + c) * DIN;
    V[o + k1] = acc0[bi];
    V[o + k2] = acc1[bi];
  }
}

// ---------------------------------------------------------------------------
// kD: sc_part[ks][b][c][l] = sum_{k chunk128} local[b][l][k]*V[b][c][k]
// grid (32 b, 3 cg12, 8 ks) = 768. 2 l per thread, 6 c per half:
// each ds_read feeds 8 FMA. threads p>=98 idle in compute (stage only).
__global__ __launch_bounds__(256) void kD_scores(
    const float* __restrict__ local_f, const float* __restrict__ V,
    float* __restrict__ A) {
  __shared__ __align__(16) float4 vs[384];          // [12][32] = 6 KB
  const int tid = threadIdx.x;
  const int b = blockIdx.x, cg = blockIdx.y, ks = blockIdx.z;
  for (int i = tid; i < 384; i += 256) {
    int ci = i >> 5, pos = i & 31;
    vs[ci * 32 + pos] = *(const float4*)&V[(size_t)(b * NCLS + cg * 12 + ci) * DIN
                                           + ks * 128 + pos * 4];
  }
  __syncthreads();
  const int g = tid >> 7, p = tid & 127;
  if (p >= 98) return;
  const int l1 = p, l2 = p + 98;
  const float* lp1 = local_f + (size_t)(b * LLOC + l1) * DIN + ks * 128;
  const float* lp2 = local_f + (size_t)(b * LLOC + l2) * DIN + ks * 128;
  float acc0[6] = {0,0,0,0,0,0};
  float acc1[6] = {0,0,0,0,0,0};
  for (int j = 0; j < 32; ++j) {
    float4 a1 = *(const float4*)&lp1[j * 4];
    float4 a2 = *(const float4*)&lp2[j * 4];
    #pragma unroll
    for (int ci = 0; ci < 6; ++ci) {
      float4 v = vs[(g * 6 + ci) * 32 + j];          // LDS broadcast
      acc0[ci] += a1.x * v.x + a1.y * v.y + a1.z * v.z + a1.w * v.w;
      acc1[ci] += a2.x * v.x + a2.y * v.y + a2.z * v.z + a2.w * v.w;
    }
  }
  #pragma unroll
  for (int ci = 0; ci < 6; ++ci) {
    size_t o = (size_t)ks * SC_N + (size_t)(b * NCLS + cg * 12 + g * 6 + ci) * LLOC;
    A[o + l1] = acc0[ci];
    A[o + l2] = acc1[ci];
  }
}

// ---------------------------------------------------------------------------
// kE: sum 8 partials + softmax over l; write attn2[b][c][l]. grid (32,36) x 64.
__global__ __launch_bounds__(64) void kE_softmax(
    const float* __restrict__ A, float* __restrict__ attn2) {
  const int b = blockIdx.x, c = blockIdx.y, t = threadIdx.x;
  const size_t base = (size_t)(b * NCLS + c) * LLOC;
  float sc[4];
  int nl = 0;
  float m = -1e30f;
  for (int l = t; l < LLOC; l += 64) {
    float s = 0.f;
    #pragma unroll
    for (int p = 0; p < 8; ++p) s += A[(size_t)p * SC_N + base + l];
    sc[nl++] = s; m = fmaxf(m, s);
  }
  #pragma unroll
  for (int off = 32; off >= 1; off >>= 1) m = fmaxf(m, __shfl_xor(m, off));
  float sum = 0.f;
  for (int i = 0; i < nl; ++i) { sc[i] = __expf(sc[i] - m); sum += sc[i]; }
  #pragma unroll
  for (int off = 32; off >= 1; off >>= 1) sum += __shfl_xor(sum, off);
  float inv = 1.0f / sum;
  nl = 0;
  for (int l = t; l < LLOC; l += 64) attn2[base + l] = sc[nl++] * inv;
}

// ---------------------------------------------------------------------------
// kF: U[b][c][k] = sum_l attn2[b][c][l]*local[b][l][k]
// grid (32 b, 8 ks128, 3 cg12) = 768. 2 k per thread, 3 c per quarter.
__global__ __launch_bounds__(256) void kF_U(
    const float* __restrict__ local_f, const float* __restrict__ attn2,
    float* __restrict__ U) {
  __shared__ __align__(16) float4 as4[588];         // [12][49] = 9.2 KB
  const int tid = threadIdx.x;
  const int b = blockIdx.x, ksf = blockIdx.y, cgf = blockIdx.z;
  for (int i = tid; i < 588; i += 256) {
    int ci = i / 49, pos = i - ci * 49;
    as4[ci * 49 + pos] = *(const float4*)&attn2[(size_t)(b * NCLS + cgf * 12 + ci) * LLOC
                                                + pos * 4];
  }
  __syncthreads();
  const int q = tid >> 6, lane = tid & 63;
  const int k1 = ksf * 128 + lane, k2 = k1 + 64;
  const int cb = q * 3;
  float acc0[3] = {0,0,0};
  float acc1[3] = {0,0,0};
  const float* lp1 = local_f + (size_t)b * LLOC * DIN + k1;
  const float* lp2 = lp1 + 64;
  for (int l4 = 0; l4 < 49; ++l4) {
    float a10 = lp1[(size_t)(l4 * 4 + 0) * DIN];
    float a11 = lp1[(size_t)(l4 * 4 + 1) * DIN];
    float a12 = lp1[(size_t)(l4 * 4 + 2) * DIN];
    float a13 = lp1[(size_t)(l4 * 4 + 3) * DIN];
    float a20 = lp2[(size_t)(l4 * 4 + 0) * DIN];
    float a21 = lp2[(size_t)(l4 * 4 + 1) * DIN];
    float a22 = lp2[(size_t)(l4 * 4 + 2) * DIN];
    float a23 = lp2[(size_t)(l4 * 4 + 3) * DIN];
    #pragma unroll
    for (int ci = 0; ci < 3; ++ci) {
      float4 w = as4[(cb + ci) * 49 + l4];           // LDS broadcast
      acc0[ci] += a10 * w.x + a11 * w.y + a12 * w.z + a13 * w.w;
      acc1[ci] += a20 * w.x + a21 * w.y + a22 * w.z + a23 * w.w;
    }
  }
  #pragma unroll
  for (int ci = 0; ci < 3; ++ci) {
    size_t o = (size_t)(b * NCLS + cgf * 12 + cb + ci) * DIN;
    U[o + k1] = acc0[ci];
    U[o + k2] = acc1[ci];
  }
}

// ---------------------------------------------------------------------------
// kG: wsh_part[ks][b][c][h] = sum_{k chunk128} U[b][c][k]*Wl[k][c*256+h]
// grid (36 c, 8 ks, 2 bh16) = 576. 2 h per thread, 8 b per half.
__global__ __launch_bounds__(256) void kG_ws(
    const float* __restrict__ Wl, const float* __restrict__ U,
    float* __restrict__ A) {
  __shared__ __align__(16) float4 us[512];          // [16][32] = 8 KB
  const int tid = threadIdx.x;
  const int c = blockIdx.x, ksg = blockIdx.y, b0 = blockIdx.z * 16;
  const int kc = ksg * 128;
  for (int i = tid; i < 512; i += 256) {
    int bi = i >> 5, pos = i & 31;
    us[bi * 32 + pos] = *(const float4*)&U[(size_t)((b0 + bi) * NCLS + c) * DIN
                                           + kc + pos * 4];
  }
  __syncthreads();
  const int g = tid >> 7, lane = tid & 127;
  float acc0[8] = {0,0,0,0,0,0,0,0};
  float acc1[8] = {0,0,0,0,0,0,0,0};
  const float* wp = Wl + (size_t)kc * NCH + c * HDIM + lane;
  for (int k4 = 0; k4 < 32; ++k4) {
    float w10 = wp[(size_t)(k4 * 4 + 0) * NCH];
    float w11 = wp[(size_t)(k4 * 4 + 1) * NCH];
    float w12 = wp[(size_t)(k4 * 4 + 2) * NCH];
    float w13 = wp[(size_t)(k4 * 4 + 3) * NCH];
    float w20 = wp[(size_t)(k4 * 4 + 0) * NCH + 128];
    float w21 = wp[(size_t)(k4 * 4 + 1) * NCH + 128];
    float w22 = wp[(size_t)(k4 * 4 + 2) * NCH + 128];
    float w23 = wp[(size_t)(k4 * 4 + 3) * NCH + 128];
    #pragma unroll
    for (int bi = 0; bi < 8; ++bi) {
      float4 u = us[(g * 8 + bi) * 32 + k4];         // LDS broadcast
      acc0[bi] += u.x * w10 + u.y * w11 + u.z * w12 + u.w * w13;
      acc1[bi] += u.x * w20 + u.y * w21 + u.z * w22 + u.w * w23;
    }
  }
  #pragma unroll
  for (int bi = 0; bi < 8; ++bi) {
    size_t o = (size_t)ksg * XG_N + (size_t)(b0 + g * 8 + bi) * NCH + c * HDIM + lane;
    A[o]       = acc0[bi];
    A[o + 128] = acc1[bi];
  }
}

// ---------------------------------------------------------------------------
// kH: ws = sum8 wsh_part + bl; hid = relu(ws@Wh+bh); heads. grid (32,12) x 256.
__global__ __launch_bounds__(256) void kH_heads(
    const float* __restrict__ Wh, const float* __restrict__ bh,
    const float* __restrict__ Wr, const float* __restrict__ br,
    const float* __restrict__ Wc, const float* __restrict__ bc,
    const float* __restrict__ bl,
    const float* __restrict__ A, float* __restrict__ out) {
  __shared__ float ws_s[3][HDIM];
  __shared__ float hid_s[3][HDIM];
  const int b = blockIdx.x, c0 = blockIdx.y * 3;
  const int j = threadIdx.x;
  #pragma unroll
  for (int ci = 0; ci < 3; ++ci) {
    size_t base = (size_t)b * NCH + (c0 + ci) * HDIM + j;
    float s = bl[(c0 + ci) * HDIM + j];
    #pragma unroll
    for (int p = 0; p < 8; ++p) s += A[(size_t)p * XG_N + base];
    ws_s[ci][j] = s;
  }
  __syncthreads();
  float acc[3] = {0,0,0};
  for (int h = 0; h < HDIM; ++h) {
    float whj = Wh[(size_t)h * HDIM + j];
    acc[0] += ws_s[0][h] * whj;
    acc[1] += ws_s[1][h] * whj;
    acc[2] += ws_s[2][h] * whj;
  }
  float bj = bh[j];
  #pragma unroll
  for (int ci = 0; ci < 3; ++ci) hid_s[ci][j] = fmaxf(acc[ci] + bj, 0.0f);
  __syncthreads();
  const int r = j >> 6, j0 = j & 63;
  for (int ci = 0; ci < 3; ++ci) {
    const int c = c0 + ci;
    float s = 0.f;
    #pragma unroll
    for (int m = 0; m < 4; ++m)
      s += hid_s[ci][j0 + 64 * m] * Wr[(j0 + 64 * m) * 4 + r];
    #pragma unroll
    for (int off = 32; off >= 1; off >>= 1) s += __shfl_xor(s, off);
    if (j0 == 0) out[(size_t)b * (NCLS * 4) + c * 4 + r] = s + br[r];
    if (r == 0) {
      float p = 0.f;
      #pragma unroll
      for (int m = 0; m < 4; ++m)
        p += hid_s[ci][j0 + 64 * m] * Wc[j0 + 64 * m];
      #pragma unroll
      for (int off = 32; off >= 1; off >>= 1) p += __shfl_xor(p, off);
      if (j0 == 0) out[BSZ * NCLS * 4 + b * NCLS + c] = p + bc[0];
    }
  }
}

// ---------------------------------------------------------------------------
extern "C" void kernel_launch(void* const* d_in, const int* in_sizes, int n_in,
                              void* d_out, int out_size, void* d_ws, size_t ws_size,
                              hipStream_t stream) {
  const float* local = (const float*)d_in[0];
  const float* gap   = (const float*)d_in[1];
  const float* Wl    = (const float*)d_in[2];
  const float* bl    = (const float*)d_in[3];
  const float* Wg    = (const float*)d_in[4];
  const float* bg    = (const float*)d_in[5];
  const float* Wh    = (const float*)d_in[6];
  const float* bh    = (const float*)d_in[7];
  const float* Wr    = (const float*)d_in[8];
  const float* br    = (const float*)d_in[9];
  const float* Wc    = (const float*)d_in[10];
  const float* bc    = (const float*)d_in[11];
  float* out         = (float*)d_out;

  // A: 8*XG_N floats — xg_part -> sc_part (8*SC_N fits) -> wsh_part.
  // V: V_N, attn2: SC_N, U: V_N. Total ~19.8 MB.
  float* A     = (float*)d_ws;
  float* V     = A + (size_t)8 * XG_N;
  float* attn2 = V + V_N;
  float* U     = attn2 + SC_N;

  kA_xg_part<<<dim3(36, 8, 2), dim3(256), 0, stream>>>(Wg, gap, A);
  kC_V      <<<dim3(36, 4, 4), dim3(256), 0, stream>>>(Wl, A, bg, V);
  kD_scores <<<dim3(32, 3, 8), dim3(256), 0, stream>>>(local, V, A);
  kE_softmax<<<dim3(32, 36),   dim3(64),  0, stream>>>(A, attn2);
  kF_U      <<<dim3(32, 8, 3), dim3(256), 0, stream>>>(local, attn2, U);
  kG_ws     <<<dim3(36, 8, 2), dim3(256), 0, stream>>>(Wl, U, A);
  kH_heads  <<<dim3(32, 12),   dim3(256), 0, stream>>>(Wh, bh, Wr, br, Wc, bc, bl, A, out);
}

// Round 9
// 267.204 us; speedup vs baseline: 1.1089x; 1.1089x over previous
//
#include <hip/hip_runtime.h>
#include <hip/hip_bf16.h>
#include <stdint.h>

#define NCLS 36
#define HDIM 256
#define BSZ  32
#define LLOC 196
#define DIN  1024
#define NCH  9216          // NCLS*HDIM
#define XG_N 294912        // BSZ*NCH
#define SC_N 225792        // BSZ*NCLS*LLOC
#define V_N  1179648       // BSZ*NCLS*DIN

// ---------------------------------------------------------------------------
// kA: xg_part[ks][b][n] = sum_{k chunk128} gap[b][k]*Wg[k][n]
// grid (36 nt256, 8 ks, 2 bh16) = 576. 2 n per thread: each ds_read feeds 8 FMA.
__global__ __launch_bounds__(256) void kA_xg_part(
    const float* __restrict__ Wg, const float* __restrict__ gap,
    float* __restrict__ A) {
  __shared__ __align__(16) float4 gs[512];          // [16][32] = 8 KB
  const int tid = threadIdx.x;
  const int nt = blockIdx.x, ks = blockIdx.y, bh = blockIdx.z;
  const int kc = ks * 128, b0 = bh * 16;
  for (int i = tid; i < 512; i += 256) {
    int bi = i >> 5, pos = i & 31;
    gs[bi * 32 + pos] = *(const float4*)&gap[(size_t)(b0 + bi) * DIN + kc + pos * 4];
  }
  __syncthreads();
  const int g = tid >> 7, lane = tid & 127;
  const int n = nt * 256 + lane;
  float acc0[8] = {0,0,0,0,0,0,0,0};
  float acc1[8] = {0,0,0,0,0,0,0,0};
  const float* wp = Wg + (size_t)kc * NCH + n;
  for (int k4 = 0; k4 < 32; ++k4) {
    float w10 = wp[(size_t)(k4 * 4 + 0) * NCH];
    float w11 = wp[(size_t)(k4 * 4 + 1) * NCH];
    float w12 = wp[(size_t)(k4 * 4 + 2) * NCH];
    float w13 = wp[(size_t)(k4 * 4 + 3) * NCH];
    float w20 = wp[(size_t)(k4 * 4 + 0) * NCH + 128];
    float w21 = wp[(size_t)(k4 * 4 + 1) * NCH + 128];
    float w22 = wp[(size_t)(k4 * 4 + 2) * NCH + 128];
    float w23 = wp[(size_t)(k4 * 4 + 3) * NCH + 128];
    #pragma unroll
    for (int bi = 0; bi < 8; ++bi) {
      float4 gv = gs[(g * 8 + bi) * 32 + k4];        // LDS broadcast
      acc0[bi] += gv.x * w10 + gv.y * w11 + gv.z * w12 + gv.w * w13;
      acc1[bi] += gv.x * w20 + gv.y * w21 + gv.z * w22 + gv.w * w23;
    }
  }
  #pragma unroll
  for (int bi = 0; bi < 8; ++bi) {
    size_t o = (size_t)ks * XG_N + (size_t)(b0 + g * 8 + bi) * NCH + n;
    A[o]       = acc0[bi];
    A[o + 128] = acc1[bi];
  }
}

// ---------------------------------------------------------------------------
// kC: V[b][c][k] = sum_h xg[b][c,h]*Wl[k][c,h], xg = bg + sum8 partials
// (folded into stage). grid (36 c, 4 kt, 2 bh16) = 288... -> (36,8,2)=576?
// Layout: lane = 4r+q; r = 16 k-rows/wave, q = 4 h-offsets -> every Wl
// wave-load touches 16 FULL cache lines (no 64-line gather). 2 k x 16 b accs
// per thread; q-partials combined with 2 shfl_xor.
__global__ __launch_bounds__(256) void kC_V(
    const float* __restrict__ Wl, const float* __restrict__ A,
    const float* __restrict__ bg, float* __restrict__ V) {
  __shared__ __align__(16) float4 xg_s[1024];       // [16 b][64 hq] = 16 KB
  const int tid = threadIdx.x;
  const int c  = blockIdx.x;
  const int kt = blockIdx.y;          // 0..7 -> 128-k tile
  const int b0 = blockIdx.z * 16;

  // stage: xg_s[b][hq] = bg + sum8 xg_part   (coalesced, conflict-free)
  const float4* bg4 = (const float4*)bg;
  for (int i = tid; i < 1024; i += 256) {
    int bi = i >> 6, hq = i & 63;
    float4 s = bg4[c * 64 + hq];
    size_t off4 = ((size_t)(b0 + bi) * NCH >> 2) + c * 64 + hq;
    #pragma unroll
    for (int p = 0; p < 8; ++p) {
      float4 t = *((const float4*)A + (size_t)p * (XG_N / 4) + off4);
      s.x += t.x; s.y += t.y; s.z += t.z; s.w += t.w;
    }
    xg_s[bi * 64 + hq] = s;
  }
  __syncthreads();

  const int w    = tid >> 6;          // wave id: 32-k subtile
  const int lane = tid & 63;
  const int q    = lane & 3;          // h-offset group
  const int r    = lane >> 2;         // k-row within subtile
  const int k1   = kt * 128 + w * 32 + r;
  const int k2   = k1 + 16;

  float acc0[16] = {0,0,0,0,0,0,0,0,0,0,0,0,0,0,0,0};
  float acc1[16] = {0,0,0,0,0,0,0,0,0,0,0,0,0,0,0,0};
  const float* wl1 = Wl + (size_t)k1 * NCH + c * HDIM + q * 4;
  const float* wl2 = Wl + (size_t)k2 * NCH + c * HDIM + q * 4;
  #pragma unroll 4
  for (int it = 0; it < 16; ++it) {
    float4 w1 = *(const float4*)(wl1 + it * 16);    // 16 full lines / wave
    float4 w2 = *(const float4*)(wl2 + it * 16);
    #pragma unroll
    for (int bi = 0; bi < 16; ++bi) {
      float4 x = xg_s[bi * 64 + it * 4 + q];        // 4-addr broadcast
      acc0[bi] += w1.x * x.x + w1.y * x.y + w1.z * x.z + w1.w * x.w;
      acc1[bi] += w2.x * x.x + w2.y * x.y + w2.z * x.z + w2.w * x.w;
    }
  }
  // combine q-partials (lanes 4r..4r+3)
  #pragma unroll
  for (int bi = 0; bi < 16; ++bi) {
    acc0[bi] += __shfl_xor(acc0[bi], 1); acc0[bi] += __shfl_xor(acc0[bi], 2);
    acc1[bi] += __shfl_xor(acc1[bi], 1); acc1[bi] += __shfl_xor(acc1[bi], 2);
  }
  if (q == 0) {
    #pragma unroll
    for (int bi = 0; bi < 16; ++bi) {
      size_t o = (size_t)((b0 + bi) * NCLS + c) * DIN;
      V[o + k1] = acc0[bi];
      V[o + k2] = acc1[bi];
    }
  }
}

// ---------------------------------------------------------------------------
// kD: sc_part[ks][b][c][l] = sum_{k chunk128} local[b][l][k]*V[b][c][k]
// grid (32 b, 3 cg12, 8 ks) = 768. 2 l per thread, 6 c per half.
__global__ __launch_bounds__(256) void kD_scores(
    const float* __restrict__ local_f, const float* __restrict__ V,
    float* __restrict__ A) {
  __shared__ __align__(16) float4 vs[384];          // [12][32] = 6 KB
  const int tid = threadIdx.x;
  const int b = blockIdx.x, cg = blockIdx.y, ks = blockIdx.z;
  for (int i = tid; i < 384; i += 256) {
    int ci = i >> 5, pos = i & 31;
    vs[ci * 32 + pos] = *(const float4*)&V[(size_t)(b * NCLS + cg * 12 + ci) * DIN
                                           + ks * 128 + pos * 4];
  }
  __syncthreads();
  const int g = tid >> 7, p = tid & 127;
  if (p >= 98) return;
  const int l1 = p, l2 = p + 98;
  const float* lp1 = local_f + (size_t)(b * LLOC + l1) * DIN + ks * 128;
  const float* lp2 = local_f + (size_t)(b * LLOC + l2) * DIN + ks * 128;
  float acc0[6] = {0,0,0,0,0,0};
  float acc1[6] = {0,0,0,0,0,0};
  for (int j = 0; j < 32; ++j) {
    float4 a1 = *(const float4*)&lp1[j * 4];
    float4 a2 = *(const float4*)&lp2[j * 4];
    #pragma unroll
    for (int ci = 0; ci < 6; ++ci) {
      float4 v = vs[(g * 6 + ci) * 32 + j];          // LDS broadcast
      acc0[ci] += a1.x * v.x + a1.y * v.y + a1.z * v.z + a1.w * v.w;
      acc1[ci] += a2.x * v.x + a2.y * v.y + a2.z * v.z + a2.w * v.w;
    }
  }
  #pragma unroll
  for (int ci = 0; ci < 6; ++ci) {
    size_t o = (size_t)ks * SC_N + (size_t)(b * NCLS + cg * 12 + g * 6 + ci) * LLOC;
    A[o + l1] = acc0[ci];
    A[o + l2] = acc1[ci];
  }
}

// ---------------------------------------------------------------------------
// kE: sum 8 partials + softmax over l; write attn2[b][c][l]. grid (32,36) x 64.
__global__ __launch_bounds__(64) void kE_softmax(
    const float* __restrict__ A, float* __restrict__ attn2) {
  const int b = blockIdx.x, c = blockIdx.y, t = threadIdx.x;
  const size_t base = (size_t)(b * NCLS + c) * LLOC;
  float sc[4];
  int nl = 0;
  float m = -1e30f;
  for (int l = t; l < LLOC; l += 64) {
    float s = 0.f;
    #pragma unroll
    for (int p = 0; p < 8; ++p) s += A[(size_t)p * SC_N + base + l];
    sc[nl++] = s; m = fmaxf(m, s);
  }
  #pragma unroll
  for (int off = 32; off >= 1; off >>= 1) m = fmaxf(m, __shfl_xor(m, off));
  float sum = 0.f;
  for (int i = 0; i < nl; ++i) { sc[i] = __expf(sc[i] - m); sum += sc[i]; }
  #pragma unroll
  for (int off = 32; off >= 1; off >>= 1) sum += __shfl_xor(sum, off);
  float inv = 1.0f / sum;
  nl = 0;
  for (int l = t; l < LLOC; l += 64) attn2[base + l] = sc[nl++] * inv;
}

// ---------------------------------------------------------------------------
// kF: U[b][c][k] = sum_l attn2[b][c][l]*local[b][l][k]
// grid (32 b, 8 ks128, 3 cg12) = 768. 2 k per thread, 3 c per quarter.
__global__ __launch_bounds__(256) void kF_U(
    const float* __restrict__ local_f, const float* __restrict__ attn2,
    float* __restrict__ U) {
  __shared__ __align__(16) float4 as4[588];         // [12][49] = 9.2 KB
  const int tid = threadIdx.x;
  const int b = blockIdx.x, ksf = blockIdx.y, cgf = blockIdx.z;
  for (int i = tid; i < 588; i += 256) {
    int ci = i / 49, pos = i - ci * 49;
    as4[ci * 49 + pos] = *(const float4*)&attn2[(size_t)(b * NCLS + cgf * 12 + ci) * LLOC
                                                + pos * 4];
  }
  __syncthreads();
  const int q = tid >> 6, lane = tid & 63;
  const int k1 = ksf * 128 + lane, k2 = k1 + 64;
  const int cb = q * 3;
  float acc0[3] = {0,0,0};
  float acc1[3] = {0,0,0};
  const float* lp1 = local_f + (size_t)b * LLOC * DIN + k1;
  const float* lp2 = lp1 + 64;
  for (int l4 = 0; l4 < 49; ++l4) {
    float a10 = lp1[(size_t)(l4 * 4 + 0) * DIN];
    float a11 = lp1[(size_t)(l4 * 4 + 1) * DIN];
    float a12 = lp1[(size_t)(l4 * 4 + 2) * DIN];
    float a13 = lp1[(size_t)(l4 * 4 + 3) * DIN];
    float a20 = lp2[(size_t)(l4 * 4 + 0) * DIN];
    float a21 = lp2[(size_t)(l4 * 4 + 1) * DIN];
    float a22 = lp2[(size_t)(l4 * 4 + 2) * DIN];
    float a23 = lp2[(size_t)(l4 * 4 + 3) * DIN];
    #pragma unroll
    for (int ci = 0; ci < 3; ++ci) {
      float4 w = as4[(cb + ci) * 49 + l4];           // LDS broadcast
      acc0[ci] += a10 * w.x + a11 * w.y + a12 * w.z + a13 * w.w;
      acc1[ci] += a20 * w.x + a21 * w.y + a22 * w.z + a23 * w.w;
    }
  }
  #pragma unroll
  for (int ci = 0; ci < 3; ++ci) {
    size_t o = (size_t)(b * NCLS + cgf * 12 + cb + ci) * DIN;
    U[o + k1] = acc0[ci];
    U[o + k2] = acc1[ci];
  }
}

// ---------------------------------------------------------------------------
// kG: wsh_part[ks][b][c][h] = sum_{k chunk128} U[b][c][k]*Wl[k][c*256+h]
// grid (36 c, 8 ks, 2 bh16) = 576. 2 h per thread, 8 b per half.
__global__ __launch_bounds__(256) void kG_ws(
    const float* __restrict__ Wl, const float* __restrict__ U,
    float* __restrict__ A) {
  __shared__ __align__(16) float4 us[512];          // [16][32] = 8 KB
  const int tid = threadIdx.x;
  const int c = blockIdx.x, ksg = blockIdx.y, b0 = blockIdx.z * 16;
  const int kc = ksg * 128;
  for (int i = tid; i < 512; i += 256) {
    int bi = i >> 5, pos = i & 31;
    us[bi * 32 + pos] = *(const float4*)&U[(size_t)((b0 + bi) * NCLS + c) * DIN
                                           + kc + pos * 4];
  }
  __syncthreads();
  const int g = tid >> 7, lane = tid & 127;
  float acc0[8] = {0,0,0,0,0,0,0,0};
  float acc1[8] = {0,0,0,0,0,0,0,0};
  const float* wp = Wl + (size_t)kc * NCH + c * HDIM + lane;
  for (int k4 = 0; k4 < 32; ++k4) {
    float w10 = wp[(size_t)(k4 * 4 + 0) * NCH];
    float w11 = wp[(size_t)(k4 * 4 + 1) * NCH];
    float w12 = wp[(size_t)(k4 * 4 + 2) * NCH];
    float w13 = wp[(size_t)(k4 * 4 + 3) * NCH];
    float w20 = wp[(size_t)(k4 * 4 + 0) * NCH + 128];
    float w21 = wp[(size_t)(k4 * 4 + 1) * NCH + 128];
    float w22 = wp[(size_t)(k4 * 4 + 2) * NCH + 128];
    float w23 = wp[(size_t)(k4 * 4 + 3) * NCH + 128];
    #pragma unroll
    for (int bi = 0; bi < 8; ++bi) {
      float4 u = us[(g * 8 + bi) * 32 + k4];         // LDS broadcast
      acc0[bi] += u.x * w10 + u.y * w11 + u.z * w12 + u.w * w13;
      acc1[bi] += u.x * w20 + u.y * w21 + u.z * w22 + u.w * w23;
    }
  }
  #pragma unroll
  for (int bi = 0; bi < 8; ++bi) {
    size_t o = (size_t)ksg * XG_N + (size_t)(b0 + g * 8 + bi) * NCH + c * HDIM + lane;
    A[o]       = acc0[bi];
    A[o + 128] = acc1[bi];
  }
}

// ---------------------------------------------------------------------------
// kH: ws = sum8 wsh_part + bl; hid = relu(ws@Wh+bh); heads. grid (32,12) x 256.
__global__ __launch_bounds__(256) void kH_heads(
    const float* __restrict__ Wh, const float* __restrict__ bh,
    const float* __restrict__ Wr, const float* __restrict__ br,
    const float* __restrict__ Wc, const float* __restrict__ bc,
    const float* __restrict__ bl,
    const float* __restrict__ A, float* __restrict__ out) {
  __shared__ float ws_s[3][HDIM];
  __shared__ float hid_s[3][HDIM];
  const int b = blockIdx.x, c0 = blockIdx.y * 3;
  const int j = threadIdx.x;
  #pragma unroll
  for (int ci = 0; ci < 3; ++ci) {
    size_t base = (size_t)b * NCH + (c0 + ci) * HDIM + j;
    float s = bl[(c0 + ci) * HDIM + j];
    #pragma unroll
    for (int p = 0; p < 8; ++p) s += A[(size_t)p * XG_N + base];
    ws_s[ci][j] = s;
  }
  __syncthreads();
  float acc[3] = {0,0,0};
  for (int h = 0; h < HDIM; ++h) {
    float whj = Wh[(size_t)h * HDIM + j];
    acc[0] += ws_s[0][h] * whj;
    acc[1] += ws_s[1][h] * whj;
    acc[2] += ws_s[2][h] * whj;
  }
  float bj = bh[j];
  #pragma unroll
  for (int ci = 0; ci < 3; ++ci) hid_s[ci][j] = fmaxf(acc[ci] + bj, 0.0f);
  __syncthreads();
  const int r = j >> 6, j0 = j & 63;
  for (int ci = 0; ci < 3; ++ci) {
    const int c = c0 + ci;
    float s = 0.f;
    #pragma unroll
    for (int m = 0; m < 4; ++m)
      s += hid_s[ci][j0 + 64 * m] * Wr[(j0 + 64 * m) * 4 + r];
    #pragma unroll
    for (int off = 32; off >= 1; off >>= 1) s += __shfl_xor(s, off);
    if (j0 == 0) out[(size_t)b * (NCLS * 4) + c * 4 + r] = s + br[r];
    if (r == 0) {
      float p = 0.f;
      #pragma unroll
      for (int m = 0; m < 4; ++m)
        p += hid_s[ci][j0 + 64 * m] * Wc[j0 + 64 * m];
      #pragma unroll
      for (int off = 32; off >= 1; off >>= 1) p += __shfl_xor(p, off);
      if (j0 == 0) out[BSZ * NCLS * 4 + b * NCLS + c] = p + bc[0];
    }
  }
}

// ---------------------------------------------------------------------------
extern "C" void kernel_launch(void* const* d_in, const int* in_sizes, int n_in,
                              void* d_out, int out_size, void* d_ws, size_t ws_size,
                              hipStream_t stream) {
  const float* local = (const float*)d_in[0];
  const float* gap   = (const float*)d_in[1];
  const float* Wl    = (const float*)d_in[2];
  const float* bl    = (const float*)d_in[3];
  const float* Wg    = (const float*)d_in[4];
  const float* bg    = (const float*)d_in[5];
  const float* Wh    = (const float*)d_in[6];
  const float* bh    = (const float*)d_in[7];
  const float* Wr    = (const float*)d_in[8];
  const float* br    = (const float*)d_in[9];
  const float* Wc    = (const float*)d_in[10];
  const float* bc    = (const float*)d_in[11];
  float* out         = (float*)d_out;

  // A: 8*XG_N floats — xg_part -> sc_part (8*SC_N fits) -> wsh_part.
  // V: V_N, attn2: SC_N, U: V_N. Total ~19.8 MB.
  float* A     = (float*)d_ws;
  float* V     = A + (size_t)8 * XG_N;
  float* attn2 = V + V_N;
  float* U     = attn2 + SC_N;

  kA_xg_part<<<dim3(36, 8, 2), dim3(256), 0, stream>>>(Wg, gap, A);
  kC_V      <<<dim3(36, 8, 2), dim3(256), 0, stream>>>(Wl, A, bg, V);
  kD_scores <<<dim3(32, 3, 8), dim3(256), 0, stream>>>(local, V, A);
  kE_softmax<<<dim3(32, 36),   dim3(64),  0, stream>>>(A, attn2);
  kF_U      <<<dim3(32, 8, 3), dim3(256), 0, stream>>>(local, attn2, U);
  kG_ws     <<<dim3(36, 8, 2), dim3(256), 0, stream>>>(Wl, U, A);
  kH_heads  <<<dim3(32, 12),   dim3(256), 0, stream>>>(Wh, bh, Wr, br, Wc, bc, bl, A, out);
}